// Round 6
// baseline (68.991 us; speedup 1.0000x reference)
//
#include <hip/hip_runtime.h>
#include <hip/hip_bf16.h>

typedef __attribute__((ext_vector_type(8))) short bf16x8;
typedef __attribute__((ext_vector_type(16))) float f32x16;
typedef __attribute__((ext_vector_type(4))) float f32x4;
typedef __attribute__((ext_vector_type(2))) float f32x2;
typedef unsigned short u16;

#define BN 2
#define HN 12
#define NN 2049
#define CN 64
#define NT 2048
#define BH 24
#define QSCL 0.1803368801111204f /* 0.125 * log2(e) */

__device__ __forceinline__ u16 f2bf(float x) {
  unsigned u = __builtin_bit_cast(unsigned, x);
  unsigned r = (u + 0x7fffu + ((u >> 16) & 1u)) >> 16;
  return (u16)r;
}

__device__ __forceinline__ unsigned cvt_pk(float lo, float hi) {
  unsigned r;
  asm("v_cvt_pk_bf16_f32 %0, %1, %2" : "=v"(r) : "v"(lo), "v"(hi));
  return r;
}

union PU {
  unsigned u[4];
  bf16x8 v;
};

// ---------------- Kernel A: rope q,k -> bf16; transpose v; fused row-0 partials ----------------
__global__ __launch_bounds__(256) void rope_pack(
    const float* __restrict__ q, const float* __restrict__ k, const float* __restrict__ v,
    const int* __restrict__ qpos, const int* __restrict__ kpos,
    u16* __restrict__ Qr, u16* __restrict__ Kr, u16* __restrict__ Vt,
    float* __restrict__ S0, float* __restrict__ Pl, float* __restrict__ Po) {
  const int bh = blockIdx.x;  // 0..23
  const int t = blockIdx.y;   // 0..31
  const int b = bh / HN;
  const int tid = threadIdx.x;
  const int wv = tid >> 6, l = tid & 63;

  __shared__ float lutc[1024], luts[1024];  // idx = pos*16 + f
  __shared__ float qs[4096], ks[4096];
  __shared__ u16 ldsV[64][72];
  __shared__ float q0s[64], k0s[64];
  __shared__ float osum[4][64];
  __shared__ float psum[4];

  const int n0 = 1 + t * 64;
  const size_t base0 = (size_t)bh * NN * CN;

  const float LF = 6.6438561897747253f / 16.0f;  // log2(100)/16
  for (int i = tid; i < 1024; i += 256) {
    const int pos = i >> 4, f = i & 15;
    const float inv = exp2f(-(float)f * LF);
    float sv, cv;
    sincosf((float)pos * inv, &sv, &cv);
    lutc[i] = cv;
    luts[i] = sv;
  }
  if (tid < 64) {
    q0s[tid] = q[base0 + tid];
    k0s[tid] = k[base0 + tid];
  }
  for (int e = tid; e < 4096; e += 256) {
    const int tok = e >> 6, c = e & 63;
    const size_t base = base0 + (size_t)(n0 + tok) * CN;
    qs[e] = q[base + c];
    ks[e] = k[base + c];
  }
  __syncthreads();

  float oacc = 0.f, pacc = 0.f;
  for (int i = 0; i < 16; ++i) {
    const int tok = i * 4 + wv;
    const int c = l;
    const int n = n0 + tok;
    const int cp = c & 31, f = cp & 15, axis = c >> 5;
    const int qp_ = qpos[((size_t)b * NN + n) * 2 + axis];
    const int kp_ = kpos[((size_t)b * NN + n) * 2 + axis];
    const float qa = qs[tok * 64 + c];
    const float ka = ks[tok * 64 + c];
    const float qrot = (cp < 16) ? -qs[tok * 64 + c + 16] : qs[tok * 64 + c - 16];
    const float krot = (cp < 16) ? -ks[tok * 64 + c + 16] : ks[tok * 64 + c - 16];
    Qr[((size_t)bh * NT + (n - 1)) * CN + c] =
        f2bf((qa * lutc[qp_ * 16 + f] + qrot * luts[qp_ * 16 + f]) * QSCL);
    Kr[((size_t)bh * NT + (n - 1)) * CN + c] =
        f2bf(ka * lutc[kp_ * 16 + f] + krot * luts[kp_ * 16 + f]);
    const float vv = v[base0 + (size_t)n * CN + c];
    ldsV[c][tok] = f2bf(vv);

    float pk = ka * q0s[c];
    float pq = qa * k0s[c];
    pk += __shfl_xor(pk, 1, 64);  pq += __shfl_xor(pq, 1, 64);
    pk += __shfl_xor(pk, 2, 64);  pq += __shfl_xor(pq, 2, 64);
    pk += __shfl_xor(pk, 4, 64);  pq += __shfl_xor(pq, 4, 64);
    pk += __shfl_xor(pk, 8, 64);  pq += __shfl_xor(pq, 8, 64);
    pk += __shfl_xor(pk, 16, 64); pq += __shfl_xor(pq, 16, 64);
    pk += __shfl_xor(pk, 32, 64); pq += __shfl_xor(pq, 32, 64);
    const float p = __builtin_amdgcn_exp2f(pk * QSCL);
    pacc += p;
    oacc += p * vv;
    if (l == 0) S0[(size_t)bh * NT + (n - 1)] = pq * QSCL;
  }
  osum[wv][l] = oacc;
  if (l == 0) psum[wv] = pacc;
  __syncthreads();

  for (int e = tid; e < 4096; e += 256) {
    const int c = e >> 6, tok = e & 63;
    Vt[((size_t)bh * CN + c) * NT + (t * 64 + tok)] = ldsV[c][tok];
  }
  if (tid < 64)
    Po[(size_t)(bh * 32 + t) * 64 + tid] =
        osum[0][tid] + osum[1][tid] + osum[2][tid] + osum[3][tid];
  if (tid == 0) Pl[bh * 32 + t] = psum[0] + psum[1] + psum[2] + psum[3];
}

// ---------------- Kernel C: combine row-0 partials (+ token-0 term) ----------------
__global__ __launch_bounds__(64) void row0_reduce(
    const float* __restrict__ q, const float* __restrict__ k, const float* __restrict__ v,
    const float* __restrict__ Pl, const float* __restrict__ Po, float* __restrict__ out) {
  const int bh = blockIdx.x;
  const int b = bh / HN, h = bh % HN;
  const int c = threadIdx.x;
  const size_t base0 = (size_t)bh * NN * CN;
  float pr = q[base0 + c] * k[base0 + c];
  pr += __shfl_xor(pr, 1, 64);
  pr += __shfl_xor(pr, 2, 64);
  pr += __shfl_xor(pr, 4, 64);
  pr += __shfl_xor(pr, 8, 64);
  pr += __shfl_xor(pr, 16, 64);
  pr += __shfl_xor(pr, 32, 64);
  const float p00 = __builtin_amdgcn_exp2f(pr * QSCL);
  float L = p00;
  float acc = p00 * v[base0 + c];
#pragma unroll
  for (int i = 0; i < 32; ++i) {
    L += Pl[bh * 32 + i];
    acc += Po[(size_t)(bh * 32 + i) * 64 + c];
  }
  out[(size_t)b * NN * (HN * CN) + h * CN + c] = acc / L;
}

// ---------------- Kernel B: flash attention, 32x32 MFMA, swapped operands ----------------
// S^T[tok][q] = mfma32(K_frag, Q_frag): lane holds q = l&31, toks (reg&3)+8*(reg>>2)+4*(l>>5).
// PV: O^T[c][q] = mfma32(V^T_frag, P_frag); V staged with token order
// sigma(p) = 16s + 4*(p>>3) + (p&3) + 8*((p>>2)&1) so lane-local P words form the B-frag.
__global__ __launch_bounds__(256) void attn_main(
    const float* __restrict__ v,
    const u16* __restrict__ Qr, const u16* __restrict__ Kr, const u16* __restrict__ Vt,
    const float* __restrict__ S0, float* __restrict__ out) {
  const int wg = blockIdx.x;  // 0..383, chunked XCD mapping: XCD x owns bh in [3x,3x+3)
  const int bh = 3 * (wg & 7) + ((wg >> 3) >> 4);
  const int qt = (wg >> 3) & 15;
  const int b = bh / HN, h = bh % HN;
  const int tid = threadIdx.x;
  const int wv = tid >> 6, l = tid & 63;
  const int l31 = l & 31, lh = l >> 5;

  __shared__ u16 ldsK[2][4096];  // dbuf 64 tok x 64 c, swizzled
  __shared__ u16 ldsV[2][4096];  // dbuf 64 c x 64 tok-pos (sigma-permuted), swizzled
  __shared__ float v0f[64];
  if (tid < 64) v0f[tid] = v[(size_t)bh * NN * CN + tid];
  __syncthreads();

  // Q B-frags: B[c][q]: lane q = l31, c = step*16 + lh*8 + j
  const int qrow = qt * 128 + wv * 32 + l31;
  const u16* qp = Qr + ((size_t)bh * NT + qrow) * CN + lh * 8;
  bf16x8 qf[4];
#pragma unroll
  for (int s = 0; s < 4; ++s) qf[s] = *reinterpret_cast<const bf16x8*>(qp + s * 16);

  const float s0l2 = S0[(size_t)bh * NT + qrow];
  const float p0 = __builtin_amdgcn_exp2f(s0l2);
  float lsum = (lh == 0) ? p0 : 0.f;

  // O^T accum: o[half][reg], c = (reg&3) + 8*(reg>>2) + 4*lh + 32*half
  f32x16 o[2];
#pragma unroll
  for (int half = 0; half < 2; ++half)
#pragma unroll
    for (int reg = 0; reg < 16; ++reg)
      o[half][reg] = p0 * v0f[(reg & 3) + 8 * (reg >> 2) + 4 * lh + 32 * half];

  const u16* Kbh = Kr + (size_t)bh * NT * CN;
  const u16* Vbh = Vt + (size_t)bh * CN * NT;
  char* ldsKc = reinterpret_cast<char*>(&ldsK[0][0]);
  char* ldsVc = reinterpret_cast<char*>(&ldsV[0][0]);

  // staging: thread owns rows srowA/srowB, 16B chunk s16 (toks 8*s16..+8 for V)
  const int s16 = tid & 7, srowA = tid >> 3, srowB = (tid >> 3) + 32;
  const int swzA = (srowA & 7) << 4, swzB = (srowB & 7) << 4;
  const int kofsA = srowA * 128 + ((s16 * 16) ^ swzA);
  const int kofsB = srowB * 128 + ((s16 * 16) ^ swzB);
  const int vb1 = 32 * (s16 >> 1) + 8 * (s16 & 1);  // sigma placement of toks 0..3 of chunk
  const int vb2 = vb1 + 16;                         // toks 4..7
  const int vofsA0 = srowA * 128 + (vb1 ^ swzA);
  const int vofsA1 = srowA * 128 + (vb2 ^ swzA);
  const int vofsB0 = srowB * 128 + (vb1 ^ swzB);
  const int vofsB1 = srowB * 128 + (vb2 ^ swzB);

  f32x4 kreg[2], vrg[2];
#define LOAD_TILE(nx)                                                                       \
  do {                                                                                      \
    kreg[0] = *reinterpret_cast<const f32x4*>(Kbh + (size_t)((nx) + srowA) * CN + s16 * 8); \
    kreg[1] = *reinterpret_cast<const f32x4*>(Kbh + (size_t)((nx) + srowB) * CN + s16 * 8); \
    vrg[0] = *reinterpret_cast<const f32x4*>(Vbh + (size_t)srowA * NT + (nx) + s16 * 8);    \
    vrg[1] = *reinterpret_cast<const f32x4*>(Vbh + (size_t)srowB * NT + (nx) + s16 * 8);    \
  } while (0)

#define STAGE_WRITE(bofs)                                        \
  do {                                                           \
    *reinterpret_cast<f32x4*>(ldsKc + (bofs) + kofsA) = kreg[0]; \
    *reinterpret_cast<f32x4*>(ldsKc + (bofs) + kofsB) = kreg[1]; \
    f32x2 t0, t1, t2, t3;                                        \
    t0[0] = vrg[0][0]; t0[1] = vrg[0][1];                        \
    t1[0] = vrg[0][2]; t1[1] = vrg[0][3];                        \
    t2[0] = vrg[1][0]; t2[1] = vrg[1][1];                        \
    t3[0] = vrg[1][2]; t3[1] = vrg[1][3];                        \
    *reinterpret_cast<f32x2*>(ldsVc + (bofs) + vofsA0) = t0;     \
    *reinterpret_cast<f32x2*>(ldsVc + (bofs) + vofsA1) = t1;     \
    *reinterpret_cast<f32x2*>(ldsVc + (bofs) + vofsB0) = t2;     \
    *reinterpret_cast<f32x2*>(ldsVc + (bofs) + vofsB1) = t3;     \
  } while (0)

  LOAD_TILE(0);
  STAGE_WRITE(0);
  LOAD_TILE(64);

#pragma unroll 2
  for (int kt = 0; kt < 32; ++kt) {
    const int cur = (kt & 1) * 8192;
    const int nxt = ((kt + 1) & 1) * 8192;
    __syncthreads();
    if (kt < 31) {
      STAGE_WRITE(nxt);
      if (kt < 30) LOAD_TILE((kt + 2) * 64);
    }

    // QK^T: S^T[th] (32 tok x 32 q), contraction over c in 4 steps
    f32x16 S[2];
#pragma unroll
    for (int th = 0; th < 2; ++th)
#pragma unroll
      for (int reg = 0; reg < 16; ++reg) S[th][reg] = 0.f;
    __builtin_amdgcn_s_setprio(1);
#pragma unroll
    for (int th = 0; th < 2; ++th) {
      const int trow = th * 32 + l31;
      const int tswz = (trow & 7) << 4;
#pragma unroll
      for (int st = 0; st < 4; ++st) {
        const bf16x8 kb = *reinterpret_cast<const bf16x8*>(
            ldsKc + cur + trow * 128 + ((st * 32 + lh * 16) ^ tswz));
        S[th] = __builtin_amdgcn_mfma_f32_32x32x16_bf16(kb, qf[st], S[th], 0, 0, 0);
      }
    }
    __builtin_amdgcn_s_setprio(0);

    // P = exp2(S); pack lane-local B-frag words (pa[s] covers tok-slice s)
    PU pa[4];
#pragma unroll
    for (int th = 0; th < 2; ++th) {
      float e[16];
#pragma unroll
      for (int reg = 0; reg < 16; ++reg) e[reg] = __builtin_amdgcn_exp2f(S[th][reg]);
#pragma unroll
      for (int reg = 0; reg < 16; reg += 4)
        lsum += (e[reg] + e[reg + 1]) + (e[reg + 2] + e[reg + 3]);
#pragma unroll
      for (int sp = 0; sp < 2; ++sp) {
#pragma unroll
        for (int m = 0; m < 4; ++m)
          pa[2 * th + sp].u[m] = cvt_pk(e[8 * sp + 2 * m], e[8 * sp + 2 * m + 1]);
      }
    }

    // PV: O^T[half] += V^T_frag . P_frag over 4 tok-slices
    __builtin_amdgcn_s_setprio(1);
#pragma unroll
    for (int half = 0; half < 2; ++half) {
      const int crow = half * 32 + l31;
      const int cswz = (crow & 7) << 4;
#pragma unroll
      for (int s = 0; s < 4; ++s) {
        const bf16x8 vb = *reinterpret_cast<const bf16x8*>(
            ldsVc + cur + crow * 128 + ((s * 32 + lh * 16) ^ cswz));
        o[half] = __builtin_amdgcn_mfma_f32_32x32x16_bf16(vb, pa[s].v, o[half], 0, 0, 0);
      }
    }
    __builtin_amdgcn_s_setprio(0);
  }

  // epilogue: full row-sum, normalize, store (lane owns q-row l31)
  float ls = lsum;
  ls += __shfl_xor(ls, 32, 64);
  const float invl = 1.0f / ls;
  const int n = 1 + qrow;
  float* op = out + ((size_t)b * NN + n) * (HN * CN) + h * CN;
#pragma unroll
  for (int half = 0; half < 2; ++half) {
#pragma unroll
    for (int rq = 0; rq < 4; ++rq) {
      f32x4 val;
#pragma unroll
      for (int j = 0; j < 4; ++j) val[j] = o[half][4 * rq + j] * invl;
      *reinterpret_cast<f32x4*>(op + 8 * rq + 4 * lh + 32 * half) = val;
    }
  }
#undef LOAD_TILE
#undef STAGE_WRITE
}

extern "C" void kernel_launch(void* const* d_in, const int* in_sizes, int n_in,
                              void* d_out, int out_size, void* d_ws, size_t ws_size,
                              hipStream_t stream) {
  const float* q = (const float*)d_in[0];
  const float* k = (const float*)d_in[1];
  const float* v = (const float*)d_in[2];
  const int* qpos = (const int*)d_in[3];
  const int* kpos = (const int*)d_in[4];
  float* out = (float*)d_out;

  u16* Qr = (u16*)d_ws;
  u16* Kr = Qr + (size_t)BH * NT * CN;
  u16* Vt = Kr + (size_t)BH * NT * CN;
  float* S0 = (float*)(Vt + (size_t)BH * NT * CN);
  float* Pl = S0 + (size_t)BH * NT;
  float* Po = Pl + BH * 32;

  rope_pack<<<dim3(BH, 32), 256, 0, stream>>>(q, k, v, qpos, kpos, Qr, Kr, Vt, S0, Pl, Po);
  row0_reduce<<<dim3(BH), 64, 0, stream>>>(q, k, v, Pl, Po, out);
  attn_main<<<dim3(BH * 16), 256, 0, stream>>>(v, Qr, Kr, Vt, S0, out);
}

// Round 7
// 64.602 us; speedup vs baseline: 1.0679x; 1.0679x over previous
//
#include <hip/hip_runtime.h>
#include <hip/hip_bf16.h>

typedef __attribute__((ext_vector_type(8))) short bf16x8;
typedef __attribute__((ext_vector_type(16))) float f32x16;
typedef __attribute__((ext_vector_type(4))) float f32x4;
typedef __attribute__((ext_vector_type(2))) float f32x2;
typedef unsigned short u16;

#define BN 2
#define HN 12
#define NN 2049
#define CN 64
#define NT 2048
#define BH 24
#define QSCL 0.1803368801111204f /* 0.125 * log2(e) */

__device__ __forceinline__ u16 f2bf(float x) {
  unsigned u = __builtin_bit_cast(unsigned, x);
  unsigned r = (u + 0x7fffu + ((u >> 16) & 1u)) >> 16;
  return (u16)r;
}

__device__ __forceinline__ unsigned cvt_pk(float lo, float hi) {
  unsigned r;
  asm("v_cvt_pk_bf16_f32 %0, %1, %2" : "=v"(r) : "v"(lo), "v"(hi));
  return r;
}

union PU {
  unsigned u[4];
  bf16x8 v;
};
union B8 {
  f32x2 h[2];
  bf16x8 v;
};

// ---------------- Kernel A: rope q,k -> bf16; transpose v; fused row-0 partials ----------------
__global__ __launch_bounds__(256) void rope_pack(
    const float* __restrict__ q, const float* __restrict__ k, const float* __restrict__ v,
    const int* __restrict__ qpos, const int* __restrict__ kpos,
    u16* __restrict__ Qr, u16* __restrict__ Kr, u16* __restrict__ Vt,
    float* __restrict__ S0, float* __restrict__ Pl, float* __restrict__ Po) {
  const int bh = blockIdx.x;  // 0..23
  const int t = blockIdx.y;   // 0..31
  const int b = bh / HN;
  const int tid = threadIdx.x;
  const int wv = tid >> 6, l = tid & 63;

  __shared__ float lutc[1024], luts[1024];  // idx = pos*16 + f
  __shared__ float qs[4096], ks[4096];
  __shared__ u16 ldsV[64][72];
  __shared__ float q0s[64], k0s[64];
  __shared__ float osum[4][64];
  __shared__ float psum[4];

  const int n0 = 1 + t * 64;
  const size_t base0 = (size_t)bh * NN * CN;

  const float LF = 6.6438561897747253f / 16.0f;  // log2(100)/16
  for (int i = tid; i < 1024; i += 256) {
    const int pos = i >> 4, f = i & 15;
    const float inv = exp2f(-(float)f * LF);
    float sv, cv;
    sincosf((float)pos * inv, &sv, &cv);
    lutc[i] = cv;
    luts[i] = sv;
  }
  if (tid < 64) {
    q0s[tid] = q[base0 + tid];
    k0s[tid] = k[base0 + tid];
  }
  for (int e = tid; e < 4096; e += 256) {
    const int tok = e >> 6, c = e & 63;
    const size_t base = base0 + (size_t)(n0 + tok) * CN;
    qs[e] = q[base + c];
    ks[e] = k[base + c];
  }
  __syncthreads();

  float oacc = 0.f, pacc = 0.f;
  for (int i = 0; i < 16; ++i) {
    const int tok = i * 4 + wv;
    const int c = l;
    const int n = n0 + tok;
    const int cp = c & 31, f = cp & 15, axis = c >> 5;
    const int qp_ = qpos[((size_t)b * NN + n) * 2 + axis];
    const int kp_ = kpos[((size_t)b * NN + n) * 2 + axis];
    const float qa = qs[tok * 64 + c];
    const float ka = ks[tok * 64 + c];
    const float qrot = (cp < 16) ? -qs[tok * 64 + c + 16] : qs[tok * 64 + c - 16];
    const float krot = (cp < 16) ? -ks[tok * 64 + c + 16] : ks[tok * 64 + c - 16];
    Qr[((size_t)bh * NT + (n - 1)) * CN + c] =
        f2bf((qa * lutc[qp_ * 16 + f] + qrot * luts[qp_ * 16 + f]) * QSCL);
    Kr[((size_t)bh * NT + (n - 1)) * CN + c] =
        f2bf(ka * lutc[kp_ * 16 + f] + krot * luts[kp_ * 16 + f]);
    const float vv = v[base0 + (size_t)n * CN + c];
    ldsV[c][tok] = f2bf(vv);

    float pk = ka * q0s[c];
    float pq = qa * k0s[c];
    pk += __shfl_xor(pk, 1, 64);  pq += __shfl_xor(pq, 1, 64);
    pk += __shfl_xor(pk, 2, 64);  pq += __shfl_xor(pq, 2, 64);
    pk += __shfl_xor(pk, 4, 64);  pq += __shfl_xor(pq, 4, 64);
    pk += __shfl_xor(pk, 8, 64);  pq += __shfl_xor(pq, 8, 64);
    pk += __shfl_xor(pk, 16, 64); pq += __shfl_xor(pq, 16, 64);
    pk += __shfl_xor(pk, 32, 64); pq += __shfl_xor(pq, 32, 64);
    const float p = __builtin_amdgcn_exp2f(pk * QSCL);
    pacc += p;
    oacc += p * vv;
    if (l == 0) S0[(size_t)bh * NT + (n - 1)] = pq * QSCL;
  }
  osum[wv][l] = oacc;
  if (l == 0) psum[wv] = pacc;
  __syncthreads();

  for (int e = tid; e < 4096; e += 256) {
    const int c = e >> 6, tok = e & 63;
    Vt[((size_t)bh * CN + c) * NT + (t * 64 + tok)] = ldsV[c][tok];
  }
  if (tid < 64)
    Po[(size_t)(bh * 32 + t) * 64 + tid] =
        osum[0][tid] + osum[1][tid] + osum[2][tid] + osum[3][tid];
  if (tid == 0) Pl[bh * 32 + t] = psum[0] + psum[1] + psum[2] + psum[3];
}

// ---------------- Kernel C: combine row-0 partials (+ token-0 term) ----------------
__global__ __launch_bounds__(64) void row0_reduce(
    const float* __restrict__ q, const float* __restrict__ k, const float* __restrict__ v,
    const float* __restrict__ Pl, const float* __restrict__ Po, float* __restrict__ out) {
  const int bh = blockIdx.x;
  const int b = bh / HN, h = bh % HN;
  const int c = threadIdx.x;
  const size_t base0 = (size_t)bh * NN * CN;
  float pr = q[base0 + c] * k[base0 + c];
  pr += __shfl_xor(pr, 1, 64);
  pr += __shfl_xor(pr, 2, 64);
  pr += __shfl_xor(pr, 4, 64);
  pr += __shfl_xor(pr, 8, 64);
  pr += __shfl_xor(pr, 16, 64);
  pr += __shfl_xor(pr, 32, 64);
  const float p00 = __builtin_amdgcn_exp2f(pr * QSCL);
  float L = p00;
  float acc = p00 * v[base0 + c];
#pragma unroll
  for (int i = 0; i < 32; ++i) {
    L += Pl[bh * 32 + i];
    acc += Po[(size_t)(bh * 32 + i) * 64 + c];
  }
  out[(size_t)b * NN * (HN * CN) + h * CN + c] = acc / L;
}

// ---------------- Kernel B: flash attention, 32x32 MFMA, kh-split waves ----------------
// wave wv: qh = wv&1 (32 q-rows), kh = wv>>1 (32 toks of the 64-tile).
// S^T = mfma32(K,Q): lane q=l31 holds toks (reg&3)+8*(reg>>2)+4*lh (+kh*32).
// PV: O^T = mfma32(V^T, P); V staged in sigma order so lane-local P words are the B-frag.
// LDS swizzle: byte ^= ((row&15)<<3), all reads/writes as b64 -> conflict-free half-waves.
__global__ __launch_bounds__(256, 3) void attn_main(
    const float* __restrict__ v,
    const u16* __restrict__ Qr, const u16* __restrict__ Kr, const u16* __restrict__ Vt,
    const float* __restrict__ S0, float* __restrict__ out) {
  const int wg = blockIdx.x;  // 0..767; chunked XCD mapping: XCD x owns bh in [3x,3x+3)
  const int bh = 3 * (wg & 7) + ((wg >> 3) >> 5);
  const int qt = (wg >> 3) & 31;
  const int b = bh / HN, h = bh % HN;
  const int tid = threadIdx.x;
  const int wv = tid >> 6, l = tid & 63;
  const int l31 = l & 31, lh = l >> 5;
  const int qh = wv & 1, kh = wv >> 1;

  __shared__ u16 ldsK[2][4096];  // dbuf 64 tok x 64 c, 8B-swizzled
  __shared__ u16 ldsV[2][4096];  // dbuf 64 c x 64 tok-pos (sigma), 8B-swizzled
  __shared__ float v0f[64];
  __shared__ float Lbuf[64];
  float* Obuf = reinterpret_cast<float*>(&ldsK[0][0]);  // reused post-loop: [2][64][32]

  if (tid < 64) v0f[tid] = v[(size_t)bh * NN * CN + tid];
  __syncthreads();

  // Q B-frags: lane q = l31, c = st*16 + lh*8 + j
  const int qrow = qt * 64 + qh * 32 + l31;
  const u16* qp = Qr + ((size_t)bh * NT + qrow) * CN + lh * 8;
  bf16x8 qf[4];
#pragma unroll
  for (int s = 0; s < 4; ++s) qf[s] = *reinterpret_cast<const bf16x8*>(qp + s * 16);

  const float s0l2 = S0[(size_t)bh * NT + qrow];
  const float p0 = __builtin_amdgcn_exp2f(s0l2);
  float lsum = (kh == 0 && lh == 0) ? p0 : 0.f;

  // O^T accum: o[half][reg], c = (reg&3) + 8*(reg>>2) + 4*lh + 32*half
  f32x16 o[2];
#pragma unroll
  for (int half = 0; half < 2; ++half)
#pragma unroll
    for (int reg = 0; reg < 16; ++reg)
      o[half][reg] =
          (kh == 0) ? p0 * v0f[(reg & 3) + 8 * (reg >> 2) + 4 * lh + 32 * half] : 0.f;

  const u16* Kbh = Kr + (size_t)bh * NT * CN;
  const u16* Vbh = Vt + (size_t)bh * CN * NT;
  char* ldsKc = reinterpret_cast<char*>(&ldsK[0][0]);
  char* ldsVc = reinterpret_cast<char*>(&ldsV[0][0]);

  // staging: thread owns rows srowA/srowB, 16B chunk s16
  const int s16 = tid & 7, srowA = tid >> 3, srowB = (tid >> 3) + 32;
  const int swA = (srowA & 15) << 3, swB = (srowB & 15) << 3;
  const int kA0 = srowA * 128 + ((s16 * 16) ^ swA);
  const int kA1 = srowA * 128 + ((s16 * 16 + 8) ^ swA);
  const int kB0 = srowB * 128 + ((s16 * 16) ^ swB);
  const int kB1 = srowB * 128 + ((s16 * 16 + 8) ^ swB);
  const int vb1 = 32 * (s16 >> 1) + 8 * (s16 & 1);  // sigma placement (toks 0..3 of chunk)
  const int vb2 = vb1 + 16;                         // toks 4..7
  const int vA0 = srowA * 128 + (vb1 ^ swA);
  const int vA1 = srowA * 128 + (vb2 ^ swA);
  const int vB0 = srowB * 128 + (vb1 ^ swB);
  const int vB1 = srowB * 128 + (vb2 ^ swB);

  f32x4 kreg[2], vrg[2];
#define LOAD_TILE(nx)                                                                       \
  do {                                                                                      \
    kreg[0] = *reinterpret_cast<const f32x4*>(Kbh + (size_t)((nx) + srowA) * CN + s16 * 8); \
    kreg[1] = *reinterpret_cast<const f32x4*>(Kbh + (size_t)((nx) + srowB) * CN + s16 * 8); \
    vrg[0] = *reinterpret_cast<const f32x4*>(Vbh + (size_t)srowA * NT + (nx) + s16 * 8);    \
    vrg[1] = *reinterpret_cast<const f32x4*>(Vbh + (size_t)srowB * NT + (nx) + s16 * 8);    \
  } while (0)

#define WR2(base, off, vec4)                                                  \
  do {                                                                        \
    f32x2 lo_, hi_;                                                           \
    lo_[0] = (vec4)[0]; lo_[1] = (vec4)[1];                                   \
    hi_[0] = (vec4)[2]; hi_[1] = (vec4)[3];                                   \
    *reinterpret_cast<f32x2*>((base) + (off##0)) = lo_;                       \
    *reinterpret_cast<f32x2*>((base) + (off##1)) = hi_;                       \
  } while (0)

#define STAGE_WRITE(bofs)               \
  do {                                  \
    WR2(ldsKc + (bofs), kA, kreg[0]);   \
    WR2(ldsKc + (bofs), kB, kreg[1]);   \
    WR2(ldsVc + (bofs), vA, vrg[0]);    \
    WR2(ldsVc + (bofs), vB, vrg[1]);    \
  } while (0)

  LOAD_TILE(0);
  STAGE_WRITE(0);
  LOAD_TILE(64);

#pragma unroll 2
  for (int kt = 0; kt < 32; ++kt) {
    const int cur = (kt & 1) * 8192;
    const int nxt = ((kt + 1) & 1) * 8192;
    __syncthreads();
    if (kt < 31) {
      STAGE_WRITE(nxt);
      if (kt < 30) LOAD_TILE((kt + 2) * 64);
    }

    // QK^T: S^T (32 toks of this kh x 32 q), contraction over c in 4 steps
    const int trow = kh * 32 + l31;
    const int tsw = (trow & 15) << 3;
    f32x16 S;
#pragma unroll
    for (int reg = 0; reg < 16; ++reg) S[reg] = 0.f;
    __builtin_amdgcn_s_setprio(1);
#pragma unroll
    for (int st = 0; st < 4; ++st) {
      B8 kb;
      const int cb = st * 32 + lh * 16;
      kb.h[0] = *reinterpret_cast<const f32x2*>(ldsKc + cur + trow * 128 + (cb ^ tsw));
      kb.h[1] = *reinterpret_cast<const f32x2*>(ldsKc + cur + trow * 128 + ((cb + 8) ^ tsw));
      S = __builtin_amdgcn_mfma_f32_32x32x16_bf16(kb.v, qf[st], S, 0, 0, 0);
    }
    __builtin_amdgcn_s_setprio(0);

    // P = exp2(S); pack lane-local B-frag words
    PU pa[2];
    {
      float e[16];
#pragma unroll
      for (int reg = 0; reg < 16; ++reg) e[reg] = __builtin_amdgcn_exp2f(S[reg]);
#pragma unroll
      for (int reg = 0; reg < 16; reg += 4)
        lsum += (e[reg] + e[reg + 1]) + (e[reg + 2] + e[reg + 3]);
#pragma unroll
      for (int m = 0; m < 4; ++m) {
        pa[0].u[m] = cvt_pk(e[2 * m], e[2 * m + 1]);
        pa[1].u[m] = cvt_pk(e[8 + 2 * m], e[9 + 2 * m]);
      }
    }

    // PV: O^T += V^T_frag . P over this wave's 2 tok-slices
    __builtin_amdgcn_s_setprio(1);
#pragma unroll
    for (int half = 0; half < 2; ++half) {
      const int crow = half * 32 + l31;
      const int csw = (crow & 15) << 3;
#pragma unroll
      for (int ks = 0; ks < 2; ++ks) {
        B8 vb;
        const int pb = (kh * 2 + ks) * 32 + lh * 16;
        vb.h[0] = *reinterpret_cast<const f32x2*>(ldsVc + cur + crow * 128 + (pb ^ csw));
        vb.h[1] = *reinterpret_cast<const f32x2*>(ldsVc + cur + crow * 128 + ((pb + 8) ^ csw));
        o[half] = __builtin_amdgcn_mfma_f32_32x32x16_bf16(vb.v, pa[ks].v, o[half], 0, 0, 0);
      }
    }
    __builtin_amdgcn_s_setprio(0);
  }

  // ---- epilogue: merge kh partials via LDS, normalize, store ----
  float wls = lsum + __shfl_xor(lsum, 32, 64);  // reduce over lh
  __syncthreads();                              // all tile reads done; Obuf reuse safe
  if (kh == 1) {
#pragma unroll
    for (int half = 0; half < 2; ++half)
#pragma unroll
      for (int reg = 0; reg < 16; ++reg) {
        const int c = (reg & 3) + 8 * (reg >> 2) + 4 * lh + 32 * half;
        Obuf[qh * 2048 + c * 32 + l31] = o[half][reg];
      }
    if (lh == 0) Lbuf[qh * 32 + l31] = wls;
  }
  __syncthreads();
  if (kh == 0) {
    const float L = wls + Lbuf[qh * 32 + l31];
    const float invl = 1.0f / L;
    const int n = 1 + qrow;
    float* op = out + ((size_t)b * NN + n) * (HN * CN) + h * CN;
#pragma unroll
    for (int half = 0; half < 2; ++half) {
#pragma unroll
      for (int rg = 0; rg < 4; ++rg) {
        f32x4 val;
#pragma unroll
        for (int j = 0; j < 4; ++j) {
          const int reg = 4 * rg + j;
          const int c = (reg & 3) + 8 * (reg >> 2) + 4 * lh + 32 * half;
          val[j] = (o[half][reg] + Obuf[qh * 2048 + c * 32 + l31]) * invl;
        }
        *reinterpret_cast<f32x4*>(op + 8 * rg + 4 * lh + 32 * half) = val;
      }
    }
  }
#undef LOAD_TILE
#undef WR2
#undef STAGE_WRITE
}

extern "C" void kernel_launch(void* const* d_in, const int* in_sizes, int n_in,
                              void* d_out, int out_size, void* d_ws, size_t ws_size,
                              hipStream_t stream) {
  const float* q = (const float*)d_in[0];
  const float* k = (const float*)d_in[1];
  const float* v = (const float*)d_in[2];
  const int* qpos = (const int*)d_in[3];
  const int* kpos = (const int*)d_in[4];
  float* out = (float*)d_out;

  u16* Qr = (u16*)d_ws;
  u16* Kr = Qr + (size_t)BH * NT * CN;
  u16* Vt = Kr + (size_t)BH * NT * CN;
  float* S0 = (float*)(Vt + (size_t)BH * NT * CN);
  float* Pl = S0 + (size_t)BH * NT;
  float* Po = Pl + BH * 32;

  rope_pack<<<dim3(BH, 32), 256, 0, stream>>>(q, k, v, qpos, kpos, Qr, Kr, Vt, S0, Pl, Po);
  row0_reduce<<<dim3(BH), 64, 0, stream>>>(q, k, v, Pl, Po, out);
  attn_main<<<dim3(BH * 32), 256, 0, stream>>>(v, Qr, Kr, Vt, S0, out);
}

// Round 8
// 63.102 us; speedup vs baseline: 1.0933x; 1.0238x over previous
//
#include <hip/hip_runtime.h>
#include <hip/hip_bf16.h>

typedef __attribute__((ext_vector_type(8))) short bf16x8;
typedef __attribute__((ext_vector_type(16))) float f32x16;
typedef __attribute__((ext_vector_type(4))) float f32x4;
typedef __attribute__((ext_vector_type(2))) float f32x2;
typedef unsigned short u16;

#define BN 2
#define HN 12
#define NN 2049
#define CN 64
#define NT 2048
#define BH 24
#define QSCL 0.1803368801111204f /* 0.125 * log2(e) */

__device__ __forceinline__ u16 f2bf(float x) {
  unsigned u = __builtin_bit_cast(unsigned, x);
  unsigned r = (u + 0x7fffu + ((u >> 16) & 1u)) >> 16;
  return (u16)r;
}

__device__ __forceinline__ unsigned cvt_pk(float lo, float hi) {
  unsigned r;
  asm("v_cvt_pk_bf16_f32 %0, %1, %2" : "=v"(r) : "v"(lo), "v"(hi));
  return r;
}

union PU {
  unsigned u[4];
  bf16x8 v;
};
union B8 {
  f32x2 h[2];
  bf16x8 v;
};

// ---------------- Kernel A: rope q,k -> bf16; transpose v; fused row-0 partials ----------------
// 32-token tiles, no q/k LDS staging (direct global reads; rot partner is an L1 hit).
__global__ __launch_bounds__(256) void rope_pack(
    const float* __restrict__ q, const float* __restrict__ k, const float* __restrict__ v,
    const int* __restrict__ qpos, const int* __restrict__ kpos,
    u16* __restrict__ Qr, u16* __restrict__ Kr, u16* __restrict__ Vt,
    float* __restrict__ S0, float* __restrict__ Pl, float* __restrict__ Po) {
  const int bh = blockIdx.x;  // 0..23
  const int t = blockIdx.y;   // 0..63 (32-token tiles)
  const int b = bh / HN;
  const int tid = threadIdx.x;
  const int wv = tid >> 6, l = tid & 63;

  __shared__ float lutc[1024], luts[1024];  // idx = pos*16 + f
  __shared__ u16 ldsV[64][36];
  __shared__ float q0s[64], k0s[64];
  __shared__ float osum[4][64];
  __shared__ float psum[4];

  const int n0 = 1 + t * 32;
  const size_t base0 = (size_t)bh * NN * CN;

  const float LF = 6.6438561897747253f / 16.0f;  // log2(100)/16
  for (int i = tid; i < 1024; i += 256) {
    const int pos = i >> 4, f = i & 15;
    const float inv = exp2f(-(float)f * LF);
    float sv, cv;
    sincosf((float)pos * inv, &sv, &cv);
    lutc[i] = cv;
    luts[i] = sv;
  }
  if (tid < 64) {
    q0s[tid] = q[base0 + tid];
    k0s[tid] = k[base0 + tid];
  }
  __syncthreads();

  float oacc = 0.f, pacc = 0.f;
#pragma unroll 2
  for (int i = 0; i < 8; ++i) {
    const int tok = i * 4 + wv;
    const int c = l;
    const int n = n0 + tok;
    const size_t base = base0 + (size_t)n * CN;
    const int cp = c & 31, f = cp & 15, axis = c >> 5;
    const int qp_ = qpos[((size_t)b * NN + n) * 2 + axis];
    const int kp_ = kpos[((size_t)b * NN + n) * 2 + axis];
    const float qa = q[base + c];
    const float ka = k[base + c];
    const float qrot = (cp < 16) ? -q[base + c + 16] : q[base + c - 16];
    const float krot = (cp < 16) ? -k[base + c + 16] : k[base + c - 16];
    Qr[((size_t)bh * NT + (n - 1)) * CN + c] =
        f2bf((qa * lutc[qp_ * 16 + f] + qrot * luts[qp_ * 16 + f]) * QSCL);
    Kr[((size_t)bh * NT + (n - 1)) * CN + c] =
        f2bf(ka * lutc[kp_ * 16 + f] + krot * luts[kp_ * 16 + f]);
    const float vv = v[base + c];
    ldsV[c][tok] = f2bf(vv);

    float pk = ka * q0s[c];
    float pq = qa * k0s[c];
    pk += __shfl_xor(pk, 1, 64);  pq += __shfl_xor(pq, 1, 64);
    pk += __shfl_xor(pk, 2, 64);  pq += __shfl_xor(pq, 2, 64);
    pk += __shfl_xor(pk, 4, 64);  pq += __shfl_xor(pq, 4, 64);
    pk += __shfl_xor(pk, 8, 64);  pq += __shfl_xor(pq, 8, 64);
    pk += __shfl_xor(pk, 16, 64); pq += __shfl_xor(pq, 16, 64);
    pk += __shfl_xor(pk, 32, 64); pq += __shfl_xor(pq, 32, 64);
    const float p = __builtin_amdgcn_exp2f(pk * QSCL);
    pacc += p;
    oacc += p * vv;
    if (l == 0) S0[(size_t)bh * NT + (n - 1)] = pq * QSCL;
  }
  osum[wv][l] = oacc;
  if (l == 0) psum[wv] = pacc;
  __syncthreads();

  for (int e = tid; e < 2048; e += 256) {
    const int c = e >> 5, tok = e & 31;
    Vt[((size_t)bh * CN + c) * NT + (t * 32 + tok)] = ldsV[c][tok];
  }
  if (tid < 64)
    Po[(size_t)(bh * 64 + t) * 64 + tid] =
        osum[0][tid] + osum[1][tid] + osum[2][tid] + osum[3][tid];
  if (tid == 0) Pl[bh * 64 + t] = psum[0] + psum[1] + psum[2] + psum[3];
}

// ---------------- Kernel C: combine row-0 partials (+ token-0 term) ----------------
__global__ __launch_bounds__(64) void row0_reduce(
    const float* __restrict__ q, const float* __restrict__ k, const float* __restrict__ v,
    const float* __restrict__ Pl, const float* __restrict__ Po, float* __restrict__ out) {
  const int bh = blockIdx.x;
  const int b = bh / HN, h = bh % HN;
  const int c = threadIdx.x;
  const size_t base0 = (size_t)bh * NN * CN;
  float pr = q[base0 + c] * k[base0 + c];
  pr += __shfl_xor(pr, 1, 64);
  pr += __shfl_xor(pr, 2, 64);
  pr += __shfl_xor(pr, 4, 64);
  pr += __shfl_xor(pr, 8, 64);
  pr += __shfl_xor(pr, 16, 64);
  pr += __shfl_xor(pr, 32, 64);
  const float p00 = __builtin_amdgcn_exp2f(pr * QSCL);
  float L = p00;
  float acc = p00 * v[base0 + c];
#pragma unroll
  for (int i = 0; i < 64; ++i) {
    L += Pl[bh * 64 + i];
    acc += Po[(size_t)(bh * 64 + i) * 64 + c];
  }
  out[(size_t)b * NN * (HN * CN) + h * CN + c] = acc / L;
}

// ---------------- Kernel B: flash attention, 32x32 MFMA, kh-split waves ----------------
// wave wv: qh = wv&1 (32 q-rows), kh = wv>>1 (32 toks of the 64-tile).
// S^T = mfma32(K,Q): lane q=l31 holds toks (reg&3)+8*(reg>>2)+4*lh (+kh*32).
// PV: O^T = mfma32(V^T, P); V staged in sigma order so lane-local P words are the B-frag.
// LDS swizzle: byte ^= ((row&15)<<3), b64 accesses.
__global__ __launch_bounds__(256, 3) void attn_main(
    const float* __restrict__ v,
    const u16* __restrict__ Qr, const u16* __restrict__ Kr, const u16* __restrict__ Vt,
    const float* __restrict__ S0, float* __restrict__ out) {
  const int wg = blockIdx.x;  // 0..767; chunked XCD mapping: XCD x owns bh in [3x,3x+3)
  const int bh = 3 * (wg & 7) + ((wg >> 3) >> 5);
  const int qt = (wg >> 3) & 31;
  const int b = bh / HN, h = bh % HN;
  const int tid = threadIdx.x;
  const int wv = tid >> 6, l = tid & 63;
  const int l31 = l & 31, lh = l >> 5;
  const int qh = wv & 1, kh = wv >> 1;

  __shared__ u16 ldsK[2][4096];  // dbuf 64 tok x 64 c, 8B-swizzled
  __shared__ u16 ldsV[2][4096];  // dbuf 64 c x 64 tok-pos (sigma), 8B-swizzled
  __shared__ float v0f[64];
  __shared__ float Lbuf[64];
  float* Obuf = reinterpret_cast<float*>(&ldsK[0][0]);  // reused post-loop: [2][64][32]

  if (tid < 64) v0f[tid] = v[(size_t)bh * NN * CN + tid];
  __syncthreads();

  // Q B-frags: lane q = l31, c = st*16 + lh*8 + j
  const int qrow = qt * 64 + qh * 32 + l31;
  const u16* qp = Qr + ((size_t)bh * NT + qrow) * CN + lh * 8;
  bf16x8 qf[4];
#pragma unroll
  for (int s = 0; s < 4; ++s) qf[s] = *reinterpret_cast<const bf16x8*>(qp + s * 16);

  const float s0l2 = S0[(size_t)bh * NT + qrow];
  const float p0 = __builtin_amdgcn_exp2f(s0l2);
  float lsum = (kh == 0 && lh == 0) ? p0 : 0.f;

  // O^T accum: o[half][reg], c = (reg&3) + 8*(reg>>2) + 4*lh + 32*half
  f32x16 o[2];
#pragma unroll
  for (int half = 0; half < 2; ++half)
#pragma unroll
    for (int reg = 0; reg < 16; ++reg)
      o[half][reg] =
          (kh == 0) ? p0 * v0f[(reg & 3) + 8 * (reg >> 2) + 4 * lh + 32 * half] : 0.f;

  const u16* Kbh = Kr + (size_t)bh * NT * CN;
  const u16* Vbh = Vt + (size_t)bh * CN * NT;
  char* ldsKc = reinterpret_cast<char*>(&ldsK[0][0]);
  char* ldsVc = reinterpret_cast<char*>(&ldsV[0][0]);

  // staging: thread owns rows srowA/srowB, 16B chunk s16
  const int s16 = tid & 7, srowA = tid >> 3, srowB = (tid >> 3) + 32;
  const int swA = (srowA & 15) << 3, swB = (srowB & 15) << 3;
  const int kA0 = srowA * 128 + ((s16 * 16) ^ swA);
  const int kA1 = srowA * 128 + ((s16 * 16 + 8) ^ swA);
  const int kB0 = srowB * 128 + ((s16 * 16) ^ swB);
  const int kB1 = srowB * 128 + ((s16 * 16 + 8) ^ swB);
  const int vb1 = 32 * (s16 >> 1) + 8 * (s16 & 1);  // sigma placement (toks 0..3 of chunk)
  const int vb2 = vb1 + 16;                         // toks 4..7
  const int vA0 = srowA * 128 + (vb1 ^ swA);
  const int vA1 = srowA * 128 + (vb2 ^ swA);
  const int vB0 = srowB * 128 + (vb1 ^ swB);
  const int vB1 = srowB * 128 + (vb2 ^ swB);

  f32x4 kreg[2], vrg[2];
#define LOAD_TILE(nx)                                                                       \
  do {                                                                                      \
    kreg[0] = *reinterpret_cast<const f32x4*>(Kbh + (size_t)((nx) + srowA) * CN + s16 * 8); \
    kreg[1] = *reinterpret_cast<const f32x4*>(Kbh + (size_t)((nx) + srowB) * CN + s16 * 8); \
    vrg[0] = *reinterpret_cast<const f32x4*>(Vbh + (size_t)srowA * NT + (nx) + s16 * 8);    \
    vrg[1] = *reinterpret_cast<const f32x4*>(Vbh + (size_t)srowB * NT + (nx) + s16 * 8);    \
  } while (0)

#define WR2(base, off, vec4)                                                  \
  do {                                                                        \
    f32x2 lo_, hi_;                                                           \
    lo_[0] = (vec4)[0]; lo_[1] = (vec4)[1];                                   \
    hi_[0] = (vec4)[2]; hi_[1] = (vec4)[3];                                   \
    *reinterpret_cast<f32x2*>((base) + (off##0)) = lo_;                       \
    *reinterpret_cast<f32x2*>((base) + (off##1)) = hi_;                       \
  } while (0)

#define STAGE_WRITE(bofs)               \
  do {                                  \
    WR2(ldsKc + (bofs), kA, kreg[0]);   \
    WR2(ldsKc + (bofs), kB, kreg[1]);   \
    WR2(ldsVc + (bofs), vA, vrg[0]);    \
    WR2(ldsVc + (bofs), vB, vrg[1]);    \
  } while (0)

  LOAD_TILE(0);
  STAGE_WRITE(0);
  LOAD_TILE(64);

#pragma unroll 2
  for (int kt = 0; kt < 32; ++kt) {
    const int cur = (kt & 1) * 8192;
    const int nxt = ((kt + 1) & 1) * 8192;
    __syncthreads();
    if (kt < 31) {
      STAGE_WRITE(nxt);
      if (kt < 30) LOAD_TILE((kt + 2) * 64);
    }

    // QK^T: S^T (32 toks of this kh x 32 q); two independent 2-MFMA chains
    const int trow = kh * 32 + l31;
    const int tsw = (trow & 15) << 3;
    f32x16 Sa, Sb;
#pragma unroll
    for (int reg = 0; reg < 16; ++reg) {
      Sa[reg] = 0.f;
      Sb[reg] = 0.f;
    }
    __builtin_amdgcn_s_setprio(1);
#pragma unroll
    for (int st = 0; st < 4; ++st) {
      B8 kb;
      const int cb = st * 32 + lh * 16;
      kb.h[0] = *reinterpret_cast<const f32x2*>(ldsKc + cur + trow * 128 + (cb ^ tsw));
      kb.h[1] = *reinterpret_cast<const f32x2*>(ldsKc + cur + trow * 128 + ((cb + 8) ^ tsw));
      if (st < 2)
        Sa = __builtin_amdgcn_mfma_f32_32x32x16_bf16(kb.v, qf[st], Sa, 0, 0, 0);
      else
        Sb = __builtin_amdgcn_mfma_f32_32x32x16_bf16(kb.v, qf[st], Sb, 0, 0, 0);
    }
    __builtin_amdgcn_s_setprio(0);

    // P = exp2(Sa+Sb); pack lane-local B-frag words
    PU pa[2];
    {
      float e[16];
#pragma unroll
      for (int reg = 0; reg < 16; ++reg)
        e[reg] = __builtin_amdgcn_exp2f(Sa[reg] + Sb[reg]);
#pragma unroll
      for (int reg = 0; reg < 16; reg += 4)
        lsum += (e[reg] + e[reg + 1]) + (e[reg + 2] + e[reg + 3]);
#pragma unroll
      for (int m = 0; m < 4; ++m) {
        pa[0].u[m] = cvt_pk(e[2 * m], e[2 * m + 1]);
        pa[1].u[m] = cvt_pk(e[8 + 2 * m], e[9 + 2 * m]);
      }
    }

    // PV: O^T += V^T_frag . P over this wave's 2 tok-slices
    __builtin_amdgcn_s_setprio(1);
#pragma unroll
    for (int half = 0; half < 2; ++half) {
      const int crow = half * 32 + l31;
      const int csw = (crow & 15) << 3;
#pragma unroll
      for (int ks = 0; ks < 2; ++ks) {
        B8 vb;
        const int pb = (kh * 2 + ks) * 32 + lh * 16;
        vb.h[0] = *reinterpret_cast<const f32x2*>(ldsVc + cur + crow * 128 + (pb ^ csw));
        vb.h[1] = *reinterpret_cast<const f32x2*>(ldsVc + cur + crow * 128 + ((pb + 8) ^ csw));
        o[half] = __builtin_amdgcn_mfma_f32_32x32x16_bf16(vb.v, pa[ks].v, o[half], 0, 0, 0);
      }
    }
    __builtin_amdgcn_s_setprio(0);
  }

  // ---- epilogue: merge kh partials via LDS, normalize, store ----
  float wls = lsum + __shfl_xor(lsum, 32, 64);  // reduce over lh
  __syncthreads();                              // all tile reads done; Obuf reuse safe
  if (kh == 1) {
#pragma unroll
    for (int half = 0; half < 2; ++half)
#pragma unroll
      for (int reg = 0; reg < 16; ++reg) {
        const int c = (reg & 3) + 8 * (reg >> 2) + 4 * lh + 32 * half;
        Obuf[qh * 2048 + c * 32 + l31] = o[half][reg];
      }
    if (lh == 0) Lbuf[qh * 32 + l31] = wls;
  }
  __syncthreads();
  if (kh == 0) {
    const float L = wls + Lbuf[qh * 32 + l31];
    const float invl = 1.0f / L;
    const int n = 1 + qrow;
    float* op = out + ((size_t)b * NN + n) * (HN * CN) + h * CN;
#pragma unroll
    for (int half = 0; half < 2; ++half) {
#pragma unroll
      for (int rg = 0; rg < 4; ++rg) {
        f32x4 val;
#pragma unroll
        for (int j = 0; j < 4; ++j) {
          const int reg = 4 * rg + j;
          const int c = (reg & 3) + 8 * (reg >> 2) + 4 * lh + 32 * half;
          val[j] = (o[half][reg] + Obuf[qh * 2048 + c * 32 + l31]) * invl;
        }
        *reinterpret_cast<f32x4*>(op + 8 * rg + 4 * lh + 32 * half) = val;
      }
    }
  }
#undef LOAD_TILE
#undef WR2
#undef STAGE_WRITE
}

extern "C" void kernel_launch(void* const* d_in, const int* in_sizes, int n_in,
                              void* d_out, int out_size, void* d_ws, size_t ws_size,
                              hipStream_t stream) {
  const float* q = (const float*)d_in[0];
  const float* k = (const float*)d_in[1];
  const float* v = (const float*)d_in[2];
  const int* qpos = (const int*)d_in[3];
  const int* kpos = (const int*)d_in[4];
  float* out = (float*)d_out;

  u16* Qr = (u16*)d_ws;
  u16* Kr = Qr + (size_t)BH * NT * CN;
  u16* Vt = Kr + (size_t)BH * NT * CN;
  float* S0 = (float*)(Vt + (size_t)BH * NT * CN);
  float* Pl = S0 + (size_t)BH * NT;
  float* Po = Pl + BH * 64;

  rope_pack<<<dim3(BH, 64), 256, 0, stream>>>(q, k, v, qpos, kpos, Qr, Kr, Vt, S0, Pl, Po);
  row0_reduce<<<dim3(BH), 64, 0, stream>>>(q, k, v, Pl, Po, out);
  attn_main<<<dim3(BH * 32), 256, 0, stream>>>(v, Qr, Kr, Vt, S0, out);
}